// Round 5
// baseline (183.076 us; speedup 1.0000x reference)
//
#include <hip/hip_runtime.h>

#define L 256
#define D 256
#define H 8
#define DH 32

static constexpr float NEGV = -4294967296.0f;       // fp32(-(2^32)+1)
static constexpr float INV_SQRT_DH = 0.17677669529663687f;  // 1/sqrt(32)

// ---------------------------------------------------------------------------
// Fused QKV projection: out = A @ W + bias (+ add)
// ---------------------------------------------------------------------------
__global__ __launch_bounds__(256) void proj3_kernel(
    const float* __restrict__ queries, const float* __restrict__ keys,
    const float* __restrict__ Wq, const float* __restrict__ bq,
    const float* __restrict__ Wk, const float* __restrict__ bk,
    const float* __restrict__ Wv, const float* __restrict__ bv,
    const float* __restrict__ pk, const float* __restrict__ pv,
    float* __restrict__ Qo, float* __restrict__ KPko, float* __restrict__ VPvo)
{
    __shared__ float As[16][68];
    __shared__ float Bs[16][64];

    const float* A; const float* W; const float* bias; const float* add; float* out;
    if (blockIdx.z == 0)      { A = queries; W = Wq; bias = bq; add = nullptr; out = Qo; }
    else if (blockIdx.z == 1) { A = keys;    W = Wk; bias = bk; add = pk;      out = KPko; }
    else                      { A = keys;    W = Wv; bias = bv; add = pv;      out = VPvo; }

    const int t  = threadIdx.x;
    const int bm = blockIdx.x * 64;
    const int bn = blockIdx.y * 64;

    const int ar = t >> 2;
    const int ak = (t & 3) << 2;
    const int br = t >> 4;
    const int bc = (t & 15) << 2;
    const int tm = (t >> 4) << 2;
    const int tn = (t & 15) << 2;

    float acc[4][4] = {};

    for (int k0 = 0; k0 < 256; k0 += 16) {
        const float4 a4 = *(const float4*)&A[(bm + ar) * 256 + k0 + ak];
        const float4 b4 = *(const float4*)&W[(k0 + br) * 256 + bn + bc];
        As[ak + 0][ar] = a4.x; As[ak + 1][ar] = a4.y;
        As[ak + 2][ar] = a4.z; As[ak + 3][ar] = a4.w;
        *(float4*)&Bs[br][bc] = b4;
        __syncthreads();

        #pragma unroll
        for (int kk = 0; kk < 16; ++kk) {
            const float4 a = *(const float4*)&As[kk][tm];
            const float4 bb = *(const float4*)&Bs[kk][tn];
            const float aa[4] = {a.x, a.y, a.z, a.w};
            const float bbv[4] = {bb.x, bb.y, bb.z, bb.w};
            #pragma unroll
            for (int i = 0; i < 4; ++i)
                #pragma unroll
                for (int jj = 0; jj < 4; ++jj)
                    acc[i][jj] = fmaf(aa[i], bbv[jj], acc[i][jj]);
        }
        __syncthreads();
    }

    const float4 bias4 = *(const float4*)&bias[bn + tn];
    #pragma unroll
    for (int i = 0; i < 4; ++i) {
        const int row = bm + tm + i;
        float4 o;
        o.x = acc[i][0] + bias4.x; o.y = acc[i][1] + bias4.y;
        o.z = acc[i][2] + bias4.z; o.w = acc[i][3] + bias4.w;
        if (add) {
            const float4 a4 = *(const float4*)&add[row * 256 + bn + tn];
            o.x += a4.x; o.y += a4.y; o.z += a4.z; o.w += a4.w;
        }
        *(float4*)&out[row * 256 + bn + tn] = o;
    }
}

// ---------------------------------------------------------------------------
// Row-sum masks.
// ---------------------------------------------------------------------------
__global__ __launch_bounds__(256) void mask_kernel(
    const float* __restrict__ keys, const float* __restrict__ queries,
    float* __restrict__ kmask, float* __restrict__ qmask)
{
    const int wid  = (blockIdx.x * 256 + threadIdx.x) >> 6;
    const int lane = threadIdx.x & 63;
    const float* src = (wid < 2048) ? keys : queries;
    const int row = (wid < 2048) ? wid : (wid - 2048);

    const float4 v = *(const float4*)&src[row * 256 + (lane << 2)];
    float s = v.x + v.y + v.z + v.w;
    #pragma unroll
    for (int o = 1; o < 64; o <<= 1) s += __shfl_xor(s, o);
    if (lane == 0) {
        const float m = (s != 0.0f) ? 1.0f : 0.0f;
        if (wid < 2048) kmask[row] = m; else qmask[row] = m;
    }
}

// ---------------------------------------------------------------------------
// Uniform split-k pipeline.
// bid = tile*2048 + b*256 + j ; q = (b&1)?255-j:j  -> per-CU work constant.
// ---------------------------------------------------------------------------
__global__ __launch_bounds__(256) void score_kernel(
    const float* __restrict__ Qm, const float* __restrict__ KPk,
    const float* __restrict__ Tk, float* __restrict__ sc)   // sc[bq][8][256]
{
    const int bid = blockIdx.x;
    const int tt  = bid >> 11;          // k-tile 0..3
    const int bj  = bid & 2047;
    const int b   = bj >> 8;
    const int j   = bj & 255;
    const int q   = (b & 1) ? (255 - j) : j;
    const int bq  = (b << 8) + q;

    const int lo = tt << 6;
    if (lo > q) return;
    const int hi = (lo + 64 < q + 1) ? lo + 64 : q + 1;

    const int t = threadIdx.x;
    const int w = t >> 6, lane = t & 63;
    const int hB = lane >> 3, jB = lane & 7;

    const float4 qv = *(const float4*)&Qm[bq * 256 + (lane << 2)];
    const size_t tbase = (size_t)bq << 16;
    float* scout = sc + ((size_t)bq << 11);

    #pragma unroll 2
    for (int k = lo + w; k < hi; k += 4) {
        const float4 kv  = *(const float4*)&KPk[((b << 8) + k) * 256 + (lane << 2)];
        const float4 tkv = *(const float4*)&Tk[tbase + ((size_t)k << 8) + (lane << 2)];
        float p = qv.x * (kv.x + tkv.x);
        p = fmaf(qv.y, kv.y + tkv.y, p);
        p = fmaf(qv.z, kv.z + tkv.z, p);
        p = fmaf(qv.w, kv.w + tkv.w, p);
        p += __shfl_xor(p, 1);
        p += __shfl_xor(p, 2);
        p += __shfl_xor(p, 4);
        if (jB == 0) scout[(hB << 8) + k] = p;
    }
}

__global__ __launch_bounds__(256) void softmax_kernel(
    float* __restrict__ sc, const float* __restrict__ kmask,
    int* __restrict__ allneg_ws)
{
    const int bq = blockIdx.x;
    const int b  = bq >> 8;
    const int q  = bq & 255;
    const int t  = threadIdx.x;
    const int w = t >> 6, lane = t & 63;

    __shared__ float kmrow[L];
    kmrow[t] = kmask[(b << 8) + t];
    __syncthreads();

    #pragma unroll
    for (int hh = 0; hh < 2; ++hh) {
        const int h = (w << 1) + hh;
        float* row = sc + ((size_t)bq << 11) + (h << 8);
        float v[4];
        #pragma unroll
        for (int i = 0; i < 4; ++i) {
            const int k = lane + (i << 6);
            const float raw = row[k];
            v[i] = (k <= q && kmrow[k] != 0.0f) ? raw * INV_SQRT_DH : NEGV;
        }
        float m = fmaxf(fmaxf(v[0], v[1]), fmaxf(v[2], v[3]));
        #pragma unroll
        for (int o = 1; o < 64; o <<= 1) m = fmaxf(m, __shfl_xor(m, o));
        float e[4], s = 0.f;
        #pragma unroll
        for (int i = 0; i < 4; ++i) { e[i] = __expf(v[i] - m); s += e[i]; }
        #pragma unroll
        for (int o = 1; o < 64; o <<= 1) s += __shfl_xor(s, o);
        const float r = 1.0f / s;
        #pragma unroll
        for (int i = 0; i < 4; ++i) row[lane + (i << 6)] = e[i] * r;
        if (h == 0 && lane == 0) allneg_ws[bq] = (m == NEGV) ? 1 : 0;
    }
}

__global__ __launch_bounds__(256) void outp_kernel(
    const float* __restrict__ prob, const float* __restrict__ VPv,
    const float* __restrict__ Tv, const int* __restrict__ allneg_ws,
    float* __restrict__ partial)    // partial[bq][4][256]
{
    const int bid = blockIdx.x;
    const int tt  = bid >> 11;
    const int bj  = bid & 2047;
    const int b   = bj >> 8;
    const int j   = bj & 255;
    const int q   = (b & 1) ? (255 - j) : j;
    const int bq  = (b << 8) + q;

    const int t = threadIdx.x;
    const int w = t >> 6, lane = t & 63;
    const int lo = tt << 6;
    const int an = allneg_ws[bq];
    const int hi = an ? (lo + 64) : ((lo + 64 < q + 1) ? lo + 64 : q + 1);

    float* slot = partial + ((((size_t)bq << 2) + tt) << 8);

    if (lo >= hi) {     // empty tile: zero the slot
        if (t < 64)
            *(float4*)&slot[t << 2] = make_float4(0.f, 0.f, 0.f, 0.f);
        return;
    }

    __shared__ float pl[H][68];
    __shared__ float4 red[256];

    // stage prob[8][lo..lo+64) (entries beyond q are valid zeros / 1/256)
    {
        int idx = t;
        #pragma unroll
        for (int r = 0; r < 2; ++r, idx += 256) {
            const int h = idx >> 6, kk = idx & 63;
            pl[h][kk] = prob[((size_t)bq << 11) + (h << 8) + lo + kk];
        }
    }
    __syncthreads();

    const int dg = lane;
    const int h  = dg >> 3;
    const size_t tbase = (size_t)bq << 16;

    float4 acc = make_float4(0.f, 0.f, 0.f, 0.f);
    #pragma unroll 2
    for (int k = lo + w; k < hi; k += 4) {
        const float a = pl[h][k - lo];
        const float4 vv  = *(const float4*)&VPv[((b << 8) + k) * 256 + (dg << 2)];
        const float4 tvv = *(const float4*)&Tv[tbase + ((size_t)k << 8) + (dg << 2)];
        acc.x = fmaf(a, vv.x + tvv.x, acc.x);
        acc.y = fmaf(a, vv.y + tvv.y, acc.y);
        acc.z = fmaf(a, vv.z + tvv.z, acc.z);
        acc.w = fmaf(a, vv.w + tvv.w, acc.w);
    }
    red[t] = acc;
    __syncthreads();

    if (t < 64) {
        const float4 r0 = red[t], r1 = red[t + 64], r2 = red[t + 128], r3 = red[t + 192];
        float4 o;
        o.x = r0.x + r1.x + r2.x + r3.x;
        o.y = r0.y + r1.y + r2.y + r3.y;
        o.z = r0.z + r1.z + r2.z + r3.z;
        o.w = r0.w + r1.w + r2.w + r3.w;
        *(float4*)&slot[t << 2] = o;
    }
}

__global__ __launch_bounds__(64) void reduce_kernel(
    const float* __restrict__ partial, const float* __restrict__ qmask,
    const float* __restrict__ queries, float* __restrict__ out)
{
    const int bq = blockIdx.x;
    const int t  = threadIdx.x;
    const float* base = partial + (((size_t)bq << 2) << 8) + (t << 2);
    const float4 p0 = *(const float4*)(base);
    const float4 p1 = *(const float4*)(base + 256);
    const float4 p2 = *(const float4*)(base + 512);
    const float4 p3 = *(const float4*)(base + 768);
    const float qmv = qmask[bq];
    const float4 qv = *(const float4*)&queries[bq * 256 + (t << 2)];
    float4 o;
    o.x = (p0.x + p1.x + p2.x + p3.x) * qmv + qv.x;
    o.y = (p0.y + p1.y + p2.y + p3.y) * qmv + qv.y;
    o.z = (p0.z + p1.z + p2.z + p3.z) * qmv + qv.z;
    o.w = (p0.w + p1.w + p2.w + p3.w) * qmv + qv.w;
    *(float4*)&out[bq * 256 + (t << 2)] = o;
}

// ---------------------------------------------------------------------------
// Fallback monolithic attention (R3 version) for small ws.
// ---------------------------------------------------------------------------
#define LP (L + 4)

__global__ __launch_bounds__(256) void attn_kernel(
    const float* __restrict__ Qm, const float* __restrict__ KPk,
    const float* __restrict__ VPv, const float* __restrict__ Tk,
    const float* __restrict__ Tv, const float* __restrict__ kmask,
    const float* __restrict__ qmask, const float* __restrict__ queries,
    float* __restrict__ out)
{
    const int bid = blockIdx.x;
    const int b   = bid >> 8;
    const int j0  = bid & 255;
    const int q   = (b & 1) ? (255 - j0) : j0;
    const int bq  = (b << 8) + q;
    const int t  = threadIdx.x;
    const int w    = t >> 6;
    const int lane = t & 63;

    __shared__ float qrow[D];
    __shared__ float kmrow[L];
    __shared__ float sc[H][LP];
    __shared__ int   allneg[H];
    __shared__ float4 red[256];

    qrow[t]  = Qm[bq * D + t];
    kmrow[t] = kmask[(b << 8) + t];
    #pragma unroll
    for (int i = t; i < H * LP; i += 256) (&sc[0][0])[i] = NEGV;
    __syncthreads();

    const int hB = lane >> 3;
    const int jB = lane & 7;
    const size_t tbase = (size_t)bq << 16;
    const float4 qv = *(const float4*)&qrow[lane << 2];

    #pragma unroll 2
    for (int k = w; k <= q; k += 4) {
        const float4 kv  = *(const float4*)&KPk[((b << 8) + k) * 256 + (lane << 2)];
        const float4 tkv = *(const float4*)&Tk[tbase + ((size_t)k << 8) + (lane << 2)];
        float p = qv.x * (kv.x + tkv.x);
        p = fmaf(qv.y, kv.y + tkv.y, p);
        p = fmaf(qv.z, kv.z + tkv.z, p);
        p = fmaf(qv.w, kv.w + tkv.w, p);
        p += __shfl_xor(p, 1);
        p += __shfl_xor(p, 2);
        p += __shfl_xor(p, 4);
        if (jB == 0)
            sc[hB][k] = (kmrow[k] != 0.0f) ? p * INV_SQRT_DH : NEGV;
    }
    __syncthreads();

    #pragma unroll
    for (int hh = 0; hh < 2; ++hh) {
        const int h = (w << 1) + hh;
        float v0 = sc[h][lane];
        float v1 = sc[h][lane + 64];
        float v2 = sc[h][lane + 128];
        float v3 = sc[h][lane + 192];
        float m = fmaxf(fmaxf(v0, v1), fmaxf(v2, v3));
        #pragma unroll
        for (int o = 1; o < 64; o <<= 1) m = fmaxf(m, __shfl_xor(m, o));
        const float e0 = __expf(v0 - m), e1 = __expf(v1 - m);
        const float e2 = __expf(v2 - m), e3 = __expf(v3 - m);
        float s = e0 + e1 + e2 + e3;
        #pragma unroll
        for (int o = 1; o < 64; o <<= 1) s += __shfl_xor(s, o);
        const float r = 1.0f / s;
        sc[h][lane]       = e0 * r;
        sc[h][lane + 64]  = e1 * r;
        sc[h][lane + 128] = e2 * r;
        sc[h][lane + 192] = e3 * r;
        if (lane == 0) allneg[h] = (m == NEGV) ? 1 : 0;
    }
    __syncthreads();

    const int dg = lane;
    const int h  = dg >> 3;
    const int kmax = allneg[h] ? L : (q + 1);

    float4 acc = make_float4(0.f, 0.f, 0.f, 0.f);
    #pragma unroll 2
    for (int k = w; k < kmax; k += 4) {
        const float a = sc[h][k];
        const float4 v   = *(const float4*)&VPv[((b << 8) + k) * 256 + (dg << 2)];
        const float4 tvv = *(const float4*)&Tv[tbase + ((size_t)k << 8) + (dg << 2)];
        acc.x = fmaf(a, v.x + tvv.x, acc.x);
        acc.y = fmaf(a, v.y + tvv.y, acc.y);
        acc.z = fmaf(a, v.z + tvv.z, acc.z);
        acc.w = fmaf(a, v.w + tvv.w, acc.w);
    }
    red[t] = acc;
    __syncthreads();

    if (t < 64) {
        const float4 r0 = red[t], r1 = red[t + 64], r2 = red[t + 128], r3 = red[t + 192];
        const float qmv = qmask[bq];
        const float4 qv2 = *(const float4*)&queries[bq * 256 + (t << 2)];
        float4 o;
        o.x = (r0.x + r1.x + r2.x + r3.x) * qmv + qv2.x;
        o.y = (r0.y + r1.y + r2.y + r3.y) * qmv + qv2.y;
        o.z = (r0.z + r1.z + r2.z + r3.z) * qmv + qv2.z;
        o.w = (r0.w + r1.w + r2.w + r3.w) * qmv + qv2.w;
        *(float4*)&out[bq * 256 + (t << 2)] = o;
    }
}

// ---------------------------------------------------------------------------
extern "C" void kernel_launch(void* const* d_in, const int* in_sizes, int n_in,
                              void* d_out, int out_size, void* d_ws, size_t ws_size,
                              hipStream_t stream)
{
    const float* queries = (const float*)d_in[0];
    const float* keys    = (const float*)d_in[1];
    const float* Tk      = (const float*)d_in[2];
    const float* Tv      = (const float*)d_in[3];
    const float* pk      = (const float*)d_in[4];
    const float* pv      = (const float*)d_in[5];
    const float* Wq      = (const float*)d_in[6];
    const float* bq      = (const float*)d_in[7];
    const float* Wk      = (const float*)d_in[8];
    const float* bk      = (const float*)d_in[9];
    const float* Wv      = (const float*)d_in[10];
    const float* bv      = (const float*)d_in[11];
    float* out = (float*)d_out;

    float* ws  = (float*)d_ws;
    float* Q    = ws;                    // 524288
    float* KPk  = ws + 524288;           // 524288
    float* VPv  = ws + 1048576;          // 524288
    float* km   = ws + 1572864;          // 2048
    float* qm   = ws + 1574912;          // 2048
    float* sc   = ws + 1576960;          // 2048*8*256 = 4194304
    float* part = ws + 5771264;          // 2048*4*256 = 2097152
    int*   anf  = (int*)(ws + 7868416);  // 2048
    const size_t REQ = (size_t)(7868416 + 2048) * 4;

    dim3 pgrid(2048 / 64, 256 / 64, 3);
    proj3_kernel<<<pgrid, 256, 0, stream>>>(queries, keys, Wq, bq, Wk, bk,
                                            Wv, bv, pk, pv, Q, KPk, VPv);
    mask_kernel<<<1024, 256, 0, stream>>>(keys, queries, km, qm);

    if (ws_size >= REQ) {
        score_kernel<<<8192, 256, 0, stream>>>(Q, KPk, Tk, sc);
        softmax_kernel<<<2048, 256, 0, stream>>>(sc, km, anf);
        outp_kernel<<<8192, 256, 0, stream>>>(sc, VPv, Tv, anf, part);
        reduce_kernel<<<2048, 64, 0, stream>>>(part, qm, queries, out);
    } else {
        attn_kernel<<<2048, 256, 0, stream>>>(Q, KPk, VPv, Tk, Tv, km, qm, queries, out);
    }
}

// Round 6
// 158.907 us; speedup vs baseline: 1.1521x; 1.1521x over previous
//
#include <hip/hip_runtime.h>

#define L 256
#define D 256
#define H 8
#define DH 32

static constexpr float NEGV = -4294967296.0f;       // fp32(-(2^32)+1)
static constexpr float INV_SQRT_DH = 0.17677669529663687f;  // 1/sqrt(32)

// ---------------------------------------------------------------------------
// Fused QKV projection: out = A @ W + bias (+ add)
// z=0: Q   = queries@Wq + bq
// z=1: KPk = keys@Wk + bk + absolute_pos_K
// z=2: VPv = keys@Wv + bv + absolute_pos_V
// ---------------------------------------------------------------------------
__global__ __launch_bounds__(256) void proj3_kernel(
    const float* __restrict__ queries, const float* __restrict__ keys,
    const float* __restrict__ Wq, const float* __restrict__ bq,
    const float* __restrict__ Wk, const float* __restrict__ bk,
    const float* __restrict__ Wv, const float* __restrict__ bv,
    const float* __restrict__ pk, const float* __restrict__ pv,
    float* __restrict__ Qo, float* __restrict__ KPko, float* __restrict__ VPvo)
{
    __shared__ float As[16][68];
    __shared__ float Bs[16][64];

    const float* A; const float* W; const float* bias; const float* add; float* out;
    if (blockIdx.z == 0)      { A = queries; W = Wq; bias = bq; add = nullptr; out = Qo; }
    else if (blockIdx.z == 1) { A = keys;    W = Wk; bias = bk; add = pk;      out = KPko; }
    else                      { A = keys;    W = Wv; bias = bv; add = pv;      out = VPvo; }

    const int t  = threadIdx.x;
    const int bm = blockIdx.x * 64;
    const int bn = blockIdx.y * 64;

    const int ar = t >> 2;
    const int ak = (t & 3) << 2;
    const int br = t >> 4;
    const int bc = (t & 15) << 2;
    const int tm = (t >> 4) << 2;
    const int tn = (t & 15) << 2;

    float acc[4][4] = {};

    for (int k0 = 0; k0 < 256; k0 += 16) {
        const float4 a4 = *(const float4*)&A[(bm + ar) * 256 + k0 + ak];
        const float4 b4 = *(const float4*)&W[(k0 + br) * 256 + bn + bc];
        As[ak + 0][ar] = a4.x; As[ak + 1][ar] = a4.y;
        As[ak + 2][ar] = a4.z; As[ak + 3][ar] = a4.w;
        *(float4*)&Bs[br][bc] = b4;
        __syncthreads();

        #pragma unroll
        for (int kk = 0; kk < 16; ++kk) {
            const float4 a = *(const float4*)&As[kk][tm];
            const float4 bb = *(const float4*)&Bs[kk][tn];
            const float aa[4] = {a.x, a.y, a.z, a.w};
            const float bbv[4] = {bb.x, bb.y, bb.z, bb.w};
            #pragma unroll
            for (int i = 0; i < 4; ++i)
                #pragma unroll
                for (int jj = 0; jj < 4; ++jj)
                    acc[i][jj] = fmaf(aa[i], bbv[jj], acc[i][jj]);
        }
        __syncthreads();
    }

    const float4 bias4 = *(const float4*)&bias[bn + tn];
    #pragma unroll
    for (int i = 0; i < 4; ++i) {
        const int row = bm + tm + i;
        float4 o;
        o.x = acc[i][0] + bias4.x; o.y = acc[i][1] + bias4.y;
        o.z = acc[i][2] + bias4.z; o.w = acc[i][3] + bias4.w;
        if (add) {
            const float4 a4 = *(const float4*)&add[row * 256 + bn + tn];
            o.x += a4.x; o.y += a4.y; o.z += a4.z; o.w += a4.w;
        }
        *(float4*)&out[row * 256 + bn + tn] = o;
    }
}

// ---------------------------------------------------------------------------
// Row-sum masks.
// ---------------------------------------------------------------------------
__global__ __launch_bounds__(256) void mask_kernel(
    const float* __restrict__ keys, const float* __restrict__ queries,
    float* __restrict__ kmask, float* __restrict__ qmask)
{
    const int wid  = (blockIdx.x * 256 + threadIdx.x) >> 6;
    const int lane = threadIdx.x & 63;
    const float* src = (wid < 2048) ? keys : queries;
    const int row = (wid < 2048) ? wid : (wid - 2048);

    const float4 v = *(const float4*)&src[row * 256 + (lane << 2)];
    float s = v.x + v.y + v.z + v.w;
    #pragma unroll
    for (int o = 1; o < 64; o <<= 1) s += __shfl_xor(s, o);
    if (lane == 0) {
        const float m = (s != 0.0f) ? 1.0f : 0.0f;
        if (wid < 2048) kmask[row] = m; else qmask[row] = m;
    }
}

// ---------------------------------------------------------------------------
// Uniform pair-block attention: 1024 blocks x 512 threads (8 waves).
// Block (b, j) processes q = j then q = 255-j  -> every block does exactly
// 257 Tk-rows + 257 Tv-rows. Grid = 4 blocks/CU, 32 waves/CU resident for
// the entire kernel (LDS 18.3KB/block).
// ---------------------------------------------------------------------------
#define LP (L + 4)

__global__ __launch_bounds__(512) void attn_pair_kernel(
    const float* __restrict__ Qm, const float* __restrict__ KPk,
    const float* __restrict__ VPv, const float* __restrict__ Tk,
    const float* __restrict__ Tv, const float* __restrict__ kmask,
    const float* __restrict__ qmask, const float* __restrict__ queries,
    float* __restrict__ out)
{
    const int bid = blockIdx.x;          // 0..1023
    const int b   = bid >> 7;            // batch
    const int j   = bid & 127;
    const int t    = threadIdx.x;
    const int w    = t >> 6;             // wave 0..7
    const int lane = t & 63;

    __shared__ float qrow[D];
    __shared__ float kmrow[L];
    __shared__ float sc[H][LP];
    __shared__ int   allneg[H];
    __shared__ float4 red[512];

    if (t < 256) kmrow[t] = kmask[(b << 8) + t];

    #pragma unroll
    for (int pass = 0; pass < 2; ++pass) {
        const int q  = pass ? (255 - j) : j;
        const int bq = (b << 8) + q;
        const size_t tbase = (size_t)bq << 16;   // bq * L * D

        if (t < 256) qrow[t] = Qm[bq * D + t];
        for (int i = t; i < H * LP; i += 512) (&sc[0][0])[i] = NEGV;
        __syncthreads();

        // ---- Phase B: scores. 8 waves stride k by 8 (block jointly
        //      streams consecutive 1KB rows). 8-lane group per head.
        {
            const int hB = lane >> 3;
            const int jB = lane & 7;
            const float4 qv = *(const float4*)&qrow[lane << 2];
            #pragma unroll 2
            for (int k = w; k <= q; k += 8) {
                const float4 kv  = *(const float4*)&KPk[((b << 8) + k) * 256 + (lane << 2)];
                const float4 tkv = *(const float4*)&Tk[tbase + ((size_t)k << 8) + (lane << 2)];
                float p = qv.x * (kv.x + tkv.x);
                p = fmaf(qv.y, kv.y + tkv.y, p);
                p = fmaf(qv.z, kv.z + tkv.z, p);
                p = fmaf(qv.w, kv.w + tkv.w, p);
                p += __shfl_xor(p, 1);
                p += __shfl_xor(p, 2);
                p += __shfl_xor(p, 4);
                if (jB == 0)
                    sc[hB][k] = (kmrow[k] != 0.0f) ? p * INV_SQRT_DH : NEGV;
            }
        }
        __syncthreads();

        // ---- Softmax: wave w owns head w (jax semantics incl. all-NEG row).
        {
            const int h = w;
            float v0 = sc[h][lane];
            float v1 = sc[h][lane + 64];
            float v2 = sc[h][lane + 128];
            float v3 = sc[h][lane + 192];
            float m = fmaxf(fmaxf(v0, v1), fmaxf(v2, v3));
            #pragma unroll
            for (int o = 1; o < 64; o <<= 1) m = fmaxf(m, __shfl_xor(m, o));
            const float e0 = __expf(v0 - m), e1 = __expf(v1 - m);
            const float e2 = __expf(v2 - m), e3 = __expf(v3 - m);
            float s = e0 + e1 + e2 + e3;
            #pragma unroll
            for (int o = 1; o < 64; o <<= 1) s += __shfl_xor(s, o);
            const float r = 1.0f / s;
            sc[h][lane]       = e0 * r;
            sc[h][lane + 64]  = e1 * r;
            sc[h][lane + 128] = e2 * r;
            sc[h][lane + 192] = e3 * r;
            if (lane == 0) allneg[h] = (m == NEGV) ? 1 : 0;
        }
        __syncthreads();

        // ---- Phase C: out = attn @ (VPv + Tv). 8-wave k-split.
        {
            const int dg = lane;
            const int h  = dg >> 3;
            const int kmax = allneg[h] ? L : (q + 1);

            float4 acc = make_float4(0.f, 0.f, 0.f, 0.f);
            #pragma unroll 2
            for (int k = w; k < kmax; k += 8) {
                const float a = sc[h][k];
                const float4 vv  = *(const float4*)&VPv[((b << 8) + k) * 256 + (dg << 2)];
                const float4 tvv = *(const float4*)&Tv[tbase + ((size_t)k << 8) + (dg << 2)];
                acc.x = fmaf(a, vv.x + tvv.x, acc.x);
                acc.y = fmaf(a, vv.y + tvv.y, acc.y);
                acc.z = fmaf(a, vv.z + tvv.z, acc.z);
                acc.w = fmaf(a, vv.w + tvv.w, acc.w);
            }
            red[t] = acc;
        }
        __syncthreads();

        if (t < 64) {
            float4 o = make_float4(0.f, 0.f, 0.f, 0.f);
            #pragma unroll
            for (int i = 0; i < 8; ++i) {
                const float4 r4 = red[t + (i << 6)];
                o.x += r4.x; o.y += r4.y; o.z += r4.z; o.w += r4.w;
            }
            const float qmv = qmask[bq];
            const float4 qv2 = *(const float4*)&queries[bq * 256 + (t << 2)];
            o.x = o.x * qmv + qv2.x;
            o.y = o.y * qmv + qv2.y;
            o.z = o.z * qmv + qv2.z;
            o.w = o.w * qmv + qv2.w;
            *(float4*)&out[bq * 256 + (t << 2)] = o;
        }
        __syncthreads();   // protect qrow/sc/red reuse in next pass
    }
}

// ---------------------------------------------------------------------------
extern "C" void kernel_launch(void* const* d_in, const int* in_sizes, int n_in,
                              void* d_out, int out_size, void* d_ws, size_t ws_size,
                              hipStream_t stream)
{
    const float* queries = (const float*)d_in[0];
    const float* keys    = (const float*)d_in[1];
    const float* Tk      = (const float*)d_in[2];
    const float* Tv      = (const float*)d_in[3];
    const float* pk      = (const float*)d_in[4];
    const float* pv      = (const float*)d_in[5];
    const float* Wq      = (const float*)d_in[6];
    const float* bq      = (const float*)d_in[7];
    const float* Wk      = (const float*)d_in[8];
    const float* bk      = (const float*)d_in[9];
    const float* Wv      = (const float*)d_in[10];
    const float* bv      = (const float*)d_in[11];
    float* out = (float*)d_out;

    float* ws  = (float*)d_ws;
    float* Q   = ws;                    // 2048*256
    float* KPk = ws + 524288;           // 2048*256
    float* VPv = ws + 1048576;          // 2048*256
    float* km  = ws + 1572864;          // 2048
    float* qm  = ws + 1574912;          // 2048

    dim3 pgrid(2048 / 64, 256 / 64, 3);
    proj3_kernel<<<pgrid, 256, 0, stream>>>(queries, keys, Wq, bq, Wk, bk,
                                            Wv, bv, pk, pv, Q, KPk, VPv);
    mask_kernel<<<1024, 256, 0, stream>>>(keys, queries, km, qm);
    attn_pair_kernel<<<1024, 512, 0, stream>>>(Q, KPk, VPv, Tk, Tv, km, qm,
                                               queries, out);
}

// Round 7
// 148.523 us; speedup vs baseline: 1.2326x; 1.0699x over previous
//
#include <hip/hip_runtime.h>

#define L 256
#define D 256
#define H 8
#define DH 32

static constexpr float NEGV = -4294967296.0f;       // fp32(-(2^32)+1)
static constexpr float INV_SQRT_DH = 0.17677669529663687f;  // 1/sqrt(32)

// ---------------------------------------------------------------------------
// Fused QKV projection: out = A @ W + bias (+ add)
// z=0: Q   = queries@Wq + bq
// z=1: KPk = keys@Wk + bk + absolute_pos_K
// z=2: VPv = keys@Wv + bv + absolute_pos_V
// ---------------------------------------------------------------------------
__global__ __launch_bounds__(256) void proj3_kernel(
    const float* __restrict__ queries, const float* __restrict__ keys,
    const float* __restrict__ Wq, const float* __restrict__ bq,
    const float* __restrict__ Wk, const float* __restrict__ bk,
    const float* __restrict__ Wv, const float* __restrict__ bv,
    const float* __restrict__ pk, const float* __restrict__ pv,
    float* __restrict__ Qo, float* __restrict__ KPko, float* __restrict__ VPvo)
{
    __shared__ float As[16][68];
    __shared__ float Bs[16][64];

    const float* A; const float* W; const float* bias; const float* add; float* out;
    if (blockIdx.z == 0)      { A = queries; W = Wq; bias = bq; add = nullptr; out = Qo; }
    else if (blockIdx.z == 1) { A = keys;    W = Wk; bias = bk; add = pk;      out = KPko; }
    else                      { A = keys;    W = Wv; bias = bv; add = pv;      out = VPvo; }

    const int t  = threadIdx.x;
    const int bm = blockIdx.x * 64;
    const int bn = blockIdx.y * 64;

    const int ar = t >> 2;
    const int ak = (t & 3) << 2;
    const int br = t >> 4;
    const int bc = (t & 15) << 2;
    const int tm = (t >> 4) << 2;
    const int tn = (t & 15) << 2;

    float acc[4][4] = {};

    for (int k0 = 0; k0 < 256; k0 += 16) {
        const float4 a4 = *(const float4*)&A[(bm + ar) * 256 + k0 + ak];
        const float4 b4 = *(const float4*)&W[(k0 + br) * 256 + bn + bc];
        As[ak + 0][ar] = a4.x; As[ak + 1][ar] = a4.y;
        As[ak + 2][ar] = a4.z; As[ak + 3][ar] = a4.w;
        *(float4*)&Bs[br][bc] = b4;
        __syncthreads();

        #pragma unroll
        for (int kk = 0; kk < 16; ++kk) {
            const float4 a = *(const float4*)&As[kk][tm];
            const float4 bb = *(const float4*)&Bs[kk][tn];
            const float aa[4] = {a.x, a.y, a.z, a.w};
            const float bbv[4] = {bb.x, bb.y, bb.z, bb.w};
            #pragma unroll
            for (int i = 0; i < 4; ++i)
                #pragma unroll
                for (int jj = 0; jj < 4; ++jj)
                    acc[i][jj] = fmaf(aa[i], bbv[jj], acc[i][jj]);
        }
        __syncthreads();
    }

    const float4 bias4 = *(const float4*)&bias[bn + tn];
    #pragma unroll
    for (int i = 0; i < 4; ++i) {
        const int row = bm + tm + i;
        float4 o;
        o.x = acc[i][0] + bias4.x; o.y = acc[i][1] + bias4.y;
        o.z = acc[i][2] + bias4.z; o.w = acc[i][3] + bias4.w;
        if (add) {
            const float4 a4 = *(const float4*)&add[row * 256 + bn + tn];
            o.x += a4.x; o.y += a4.y; o.z += a4.z; o.w += a4.w;
        }
        *(float4*)&out[row * 256 + bn + tn] = o;
    }
}

// ---------------------------------------------------------------------------
// Row-sum masks.
// ---------------------------------------------------------------------------
__global__ __launch_bounds__(256) void mask_kernel(
    const float* __restrict__ keys, const float* __restrict__ queries,
    float* __restrict__ kmask, float* __restrict__ qmask)
{
    const int wid  = (blockIdx.x * 256 + threadIdx.x) >> 6;
    const int lane = threadIdx.x & 63;
    const float* src = (wid < 2048) ? keys : queries;
    const int row = (wid < 2048) ? wid : (wid - 2048);

    const float4 v = *(const float4*)&src[row * 256 + (lane << 2)];
    float s = v.x + v.y + v.z + v.w;
    #pragma unroll
    for (int o = 1; o < 64; o <<= 1) s += __shfl_xor(s, o);
    if (lane == 0) {
        const float m = (s != 0.0f) ? 1.0f : 0.0f;
        if (wid < 2048) kmask[row] = m; else qmask[row] = m;
    }
}

// ---------------------------------------------------------------------------
// Fused online-softmax attention: one block (256 thr / 4 waves) per (b,q).
// Single barrier-free k-loop per wave (stride 4); per-head running
// (m, l, acc) in registers; one cross-wave combine at the end.
// Lane l handles dims 4l..4l+3 (head h = l>>3); 8-lane butterfly gives the
// per-head score to exactly the lanes that accumulate that head's output.
// ---------------------------------------------------------------------------
__global__ __launch_bounds__(256) void attn_fused_kernel(
    const float* __restrict__ Qm, const float* __restrict__ KPk,
    const float* __restrict__ VPv, const float* __restrict__ Tk,
    const float* __restrict__ Tv, const float* __restrict__ kmask,
    const float* __restrict__ qmask, const float* __restrict__ queries,
    float* __restrict__ out)
{
    const int bid = blockIdx.x;
    const int b   = bid >> 8;
    const int j0  = bid & 255;
    const int q   = (b & 1) ? (255 - j0) : j0;   // balance causal work per CU
    const int bq  = (b << 8) + q;
    const int t    = threadIdx.x;
    const int w    = t >> 6;
    const int lane = t & 63;

    __shared__ float  kmrow[L];
    __shared__ float4 accL[4][64];
    __shared__ float  mL[4][64];
    __shared__ float  lL[4][64];

    kmrow[t] = kmask[(b << 8) + t];
    __syncthreads();

    const size_t tbase = (size_t)bq << 16;       // bq * L * D
    const float4 qv = *(const float4*)&Qm[bq * 256 + (lane << 2)];

    float  m  = NEGV;
    float  ls = 0.0f;
    float4 acc = make_float4(0.f, 0.f, 0.f, 0.f);

    #pragma unroll 2
    for (int k = w; k <= q; k += 4) {
        const float4 kv  = *(const float4*)&KPk[((b << 8) + k) * 256 + (lane << 2)];
        const float4 tkv = *(const float4*)&Tk[tbase + ((size_t)k << 8) + (lane << 2)];
        const float4 vv  = *(const float4*)&VPv[((b << 8) + k) * 256 + (lane << 2)];
        const float4 tvv = *(const float4*)&Tv[tbase + ((size_t)k << 8) + (lane << 2)];

        float p = qv.x * (kv.x + tkv.x);
        p = fmaf(qv.y, kv.y + tkv.y, p);
        p = fmaf(qv.z, kv.z + tkv.z, p);
        p = fmaf(qv.w, kv.w + tkv.w, p);
        p += __shfl_xor(p, 1);
        p += __shfl_xor(p, 2);
        p += __shfl_xor(p, 4);      // all 8 lanes of the head group hold the dot

        const float s = (kmrow[k] != 0.0f) ? p * INV_SQRT_DH : NEGV;
        const float mn = fmaxf(m, s);
        const float f  = __expf(m - mn);   // 1 if m unchanged; 0 from NEGV start
        const float e  = __expf(s - mn);   // exact 0 for masked k vs real max
        ls = fmaf(ls, f, e);
        acc.x = fmaf(e, vv.x + tvv.x, acc.x * f);
        acc.y = fmaf(e, vv.y + tvv.y, acc.y * f);
        acc.z = fmaf(e, vv.z + tvv.z, acc.z * f);
        acc.w = fmaf(e, vv.w + tvv.w, acc.w * f);
        m = mn;
    }

    accL[w][lane] = acc;
    mL[w][lane]   = m;
    lL[w][lane]   = ls;
    __syncthreads();

    if (t < 64) {
        const float m0 = mL[0][t], m1 = mL[1][t], m2 = mL[2][t], m3 = mL[3][t];
        const float M  = fmaxf(fmaxf(m0, m1), fmaxf(m2, m3));
        float li = 0.0f;
        float4 o = make_float4(0.f, 0.f, 0.f, 0.f);
        #pragma unroll
        for (int i = 0; i < 4; ++i) {
            const float f = __expf(mL[i][t] - M);   // exp(0)=1 in all-NEG case
            li = fmaf(lL[i][t], f, li);
            const float4 a4 = accL[i][t];
            o.x = fmaf(a4.x, f, o.x);
            o.y = fmaf(a4.y, f, o.y);
            o.z = fmaf(a4.z, f, o.z);
            o.w = fmaf(a4.w, f, o.w);
        }
        if (M == NEGV) {
            // rare: fully-masked row attends uniformly over ALL 256 keys.
            // acc already holds sum over k<=q with weight 1 each.
            for (int k = q + 1; k < L; ++k) {
                const float4 vv  = *(const float4*)&VPv[((b << 8) + k) * 256 + (t << 2)];
                const float4 tvv = *(const float4*)&Tv[tbase + ((size_t)k << 8) + (t << 2)];
                o.x += vv.x + tvv.x;
                o.y += vv.y + tvv.y;
                o.z += vv.z + tvv.z;
                o.w += vv.w + tvv.w;
            }
            li = 256.0f;
        }
        const float r   = 1.0f / li;
        const float qmv = qmask[bq];
        const float4 qv2 = *(const float4*)&queries[bq * 256 + (t << 2)];
        float4 ov;
        ov.x = o.x * r * qmv + qv2.x;
        ov.y = o.y * r * qmv + qv2.y;
        ov.z = o.z * r * qmv + qv2.z;
        ov.w = o.w * r * qmv + qv2.w;
        *(float4*)&out[bq * 256 + (t << 2)] = ov;
    }
}

// ---------------------------------------------------------------------------
extern "C" void kernel_launch(void* const* d_in, const int* in_sizes, int n_in,
                              void* d_out, int out_size, void* d_ws, size_t ws_size,
                              hipStream_t stream)
{
    const float* queries = (const float*)d_in[0];
    const float* keys    = (const float*)d_in[1];
    const float* Tk      = (const float*)d_in[2];
    const float* Tv      = (const float*)d_in[3];
    const float* pk      = (const float*)d_in[4];
    const float* pv      = (const float*)d_in[5];
    const float* Wq      = (const float*)d_in[6];
    const float* bq      = (const float*)d_in[7];
    const float* Wk      = (const float*)d_in[8];
    const float* bk      = (const float*)d_in[9];
    const float* Wv      = (const float*)d_in[10];
    const float* bv      = (const float*)d_in[11];
    float* out = (float*)d_out;

    float* ws  = (float*)d_ws;
    float* Q   = ws;                    // 2048*256
    float* KPk = ws + 524288;           // 2048*256
    float* VPv = ws + 1048576;          // 2048*256
    float* km  = ws + 1572864;          // 2048
    float* qm  = ws + 1574912;          // 2048

    dim3 pgrid(2048 / 64, 256 / 64, 3);
    proj3_kernel<<<pgrid, 256, 0, stream>>>(queries, keys, Wq, bq, Wk, bk,
                                            Wv, bv, pk, pv, Q, KPk, VPv);
    mask_kernel<<<1024, 256, 0, stream>>>(keys, queries, km, qm);
    attn_fused_kernel<<<2048, 256, 0, stream>>>(Q, KPk, VPv, Tk, Tv, km, qm,
                                                queries, out);
}